// Round 4
// baseline (496.617 us; speedup 1.0000x reference)
//
#include <hip/hip_runtime.h>
#include <hip/hip_cooperative_groups.h>
#include <math.h>

namespace cg = cooperative_groups;

#define B_  8
#define S_  2048
#define H_  256
#define HK_ 128
#define P_  64
#define NQ_ 20
#define M_  (B_*S_)          // 16384 rows
// per-batch accumulator: G[20][64]@0, E[20][64]@1280, T[64]@2560, W[20]@2624, n[20]@2644, pad->2688
#define ACC_STRIDE 2688

// ws layout (float units)
#define WS_SIM   0
#define WS_CONF  16384
#define WS_ACC   32768            // 8*2688 = 21504 floats
#define WS_WT    54272            // bf16 frags: 2*8*8*64*8 = 65536 shorts = 32768 float slots

typedef __attribute__((ext_vector_type(8))) short bf16x8;
typedef __attribute__((ext_vector_type(4))) float f32x4;

// ---------------------------------------------------------------------------
// Single cooperative kernel, 512 blocks x 256 threads (2 blocks/CU resident).
// Phase 0: round w1 RNE->bf16 into MFMA B-fragment order + zero ws_acc.
// Phase 1: dual MLP via bf16 MFMA 16x16x32, 2-term A-split, fragment loads
//          straight from global (L2), fused fp32 layer-2 epilogue.
// Phase 2: bucketed sums over param_x (G_q, E_q, T, W_q, n_q) via LDS atomics.
// Phase 3: out = c*px + (1-c) * ((T - G_q + E_q) / ((S-n_q)+W_q)).
// grid.sync() + __threadfence() between phases (cross-XCD visibility).
// ---------------------------------------------------------------------------
__launch_bounds__(256, 2)
__global__ void mega_kernel(const float* __restrict__ fx, const float* __restrict__ px,
                            const float* __restrict__ sw1, const float* __restrict__ sb1,
                            const float* __restrict__ sw2, const float* __restrict__ sb2,
                            const float* __restrict__ cw1, const float* __restrict__ cb1,
                            const float* __restrict__ cw2, const float* __restrict__ cb2,
                            const int* __restrict__ questions, float* __restrict__ out,
                            float* __restrict__ ws)
{
    cg::grid_group grid = cg::this_grid();
    float* sim    = ws + WS_SIM;
    float* conf   = ws + WS_CONF;
    float* ws_acc = ws + WS_ACC;
    short* wtf    = (short*)(ws + WS_WT);

    const int tid = threadIdx.x;
    const int bid = blockIdx.x;
    const int tg  = bid * 256 + tid;
    const int l   = tid & 63;
    const int w   = tid >> 6;
    const int col = l & 15, quad = l >> 4;

    __shared__ float accs[ACC_STRIDE];   // 10752 B, used in phase 2

    // ---------------- phase 0: prep ----------------
    if (tg < 8192) {
        const int fl = tg & 63, fnt = (tg >> 6) & 7, fkt = (tg >> 9) & 7, fmlp = tg >> 12;
        const int fcol = fl & 15, fquad = fl >> 4;
        const int n = fnt * 16 + fcol;
        const float* w1 = fmlp ? cw1 : sw1;
        short frag[8];
        #pragma unroll
        for (int j = 0; j < 8; ++j) {
            int k = fkt * 32 + fquad * 8 + j;
            union { float f; unsigned u; } c; c.f = w1[k * HK_ + n];
            frag[j] = (short)((c.u + 0x7FFF + ((c.u >> 16) & 1)) >> 16);   // RNE
        }
        *(uint4*)(wtf + (size_t)tg * 8) = *(const uint4*)frag;
    }
    {
        int zi = tg - 8192;
        if (zi >= 0 && zi < B_ * ACC_STRIDE) ws_acc[zi] = 0.f;
    }
    __threadfence();
    grid.sync();
    __threadfence();

    // ---------------- phase 1: dual MLP (32 rows/block) ----------------
    {
        const int mlp = w >> 1, mt = w & 1;
        const int row = bid * 32 + mt * 16 + col;      // A-operand m = lane&15

        f32x4 acc[8];
        #pragma unroll
        for (int nt = 0; nt < 8; ++nt) acc[nt] = (f32x4){0.f, 0.f, 0.f, 0.f};

        const float* fxrow = fx + (size_t)row * H_;
        const short* wf = wtf + (size_t)mlp * 32768 + (size_t)l * 8;

        #pragma unroll
        for (int kt = 0; kt < 8; ++kt) {
            float4 a0 = *(const float4*)(fxrow + kt * 32 + quad * 8);
            float4 a1 = *(const float4*)(fxrow + kt * 32 + quad * 8 + 4);
            float af[8] = {a0.x, a0.y, a0.z, a0.w, a1.x, a1.y, a1.z, a1.w};
            bf16x8 ahi, alo;
            #pragma unroll
            for (int i = 0; i < 8; ++i) {
                union { float f; unsigned u; } c; c.f = af[i];
                unsigned hi = c.u >> 16;                   // truncate: lo holds residual
                ahi[i] = (short)hi;
                union { float f; unsigned u; } h2; h2.u = hi << 16;
                union { float f; unsigned u; } c2; c2.f = af[i] - h2.f;
                alo[i] = (short)(c2.u >> 16);
            }
            const short* base = wf + (size_t)kt * 4096;
            #pragma unroll
            for (int nt = 0; nt < 8; ++nt) {
                bf16x8 bf = *(const bf16x8*)(base + nt * 512);
                acc[nt] = __builtin_amdgcn_mfma_f32_16x16x32_bf16(ahi, bf, acc[nt], 0, 0, 0);
                acc[nt] = __builtin_amdgcn_mfma_f32_16x16x32_bf16(alo, bf, acc[nt], 0, 0, 0);
            }
        }

        // fp32 layer-2 epilogue
        const float* b1 = mlp ? cb1 : sb1;
        const float* w2 = mlp ? cw2 : sw2;
        const float  b2v = mlp ? cb2[0] : sb2[0];
        float p[4] = {0.f, 0.f, 0.f, 0.f};
        #pragma unroll
        for (int nt = 0; nt < 8; ++nt) {
            float b1c = b1[nt * 16 + col];
            float w2c = w2[nt * 16 + col];
            #pragma unroll
            for (int j = 0; j < 4; ++j)
                p[j] += fmaxf(acc[nt][j] + b1c, 0.f) * w2c;
        }
        #pragma unroll
        for (int off = 8; off >= 1; off >>= 1)
            #pragma unroll
            for (int j = 0; j < 4; ++j) p[j] += __shfl_down(p[j], off, 16);

        if (col == 0) {
            #pragma unroll
            for (int j = 0; j < 4; ++j) {
                int r = bid * 32 + mt * 16 + quad * 4 + j;   // D row = quad*4+reg
                float v = p[j] + b2v;
                if (mlp == 0) sim[r] = v;
                else          conf[r] = 1.0f / (1.0f + expf(-v));
            }
        }
    }
    __threadfence();
    grid.sync();
    __threadfence();

    // ---------------- phase 2: bucketed accumulation (32 rows/block) ----------------
    {
        const int b = bid >> 6;            // 0..7
        const int chunk = bid & 63;        // 64 chunks of 32 rows
        const int g = w;                   // wave id 0..3
        for (int s = tid; s < ACC_STRIDE; s += 256) accs[s] = 0.f;
        __syncthreads();

        const float* simb = sim + b * S_;
        const int*   qb   = questions + b * S_;
        const float* pxb  = px + (size_t)b * S_ * P_;

        float Treg = 0.f;
        const int i0 = chunk * 32 + g;
        #pragma unroll
        for (int t = 0; t < 8; ++t) {
            int i = i0 + 4 * t;
            int qi = qb[i];                       // uniform across wave -> broadcast
            float e = expf(simb[i]);
            float v = pxb[(size_t)i * P_ + l];    // coalesced 256B per wave
            Treg += v;
            atomicAdd(&accs[qi * 64 + l], v);            // G_q
            atomicAdd(&accs[1280 + qi * 64 + l], e * v); // E_q
            if (l == 0) {
                atomicAdd(&accs[2624 + qi], e);          // W_q
                atomicAdd(&accs[2644 + qi], 1.0f);       // n_q
            }
        }
        atomicAdd(&accs[2560 + l], Treg);                // T
        __syncthreads();

        float* dst = ws_acc + (size_t)b * ACC_STRIDE;
        for (int s = tid; s < ACC_STRIDE; s += 256)
            atomicAdd(dst + s, accs[s]);
    }
    __threadfence();
    grid.sync();
    __threadfence();

    // ---------------- phase 3: output ----------------
    #pragma unroll
    for (int k = 0; k < 2; ++k) {
        const int idx = bid * 512 + k * 256 + tid;   // float4 units, 262144 total
        const int row = idx >> 4;                    // b*S + s
        const int p4  = idx & 15;
        const int b   = row >> 11;                   // S = 2048
        const float c = conf[row];
        const int   q = questions[row];
        const float* accb = ws_acc + (size_t)b * ACC_STRIDE;
        const float4 T = *(const float4*)(accb + 2560 + p4 * 4);
        const float4 G = *(const float4*)(accb + q * 64 + p4 * 4);
        const float4 E = *(const float4*)(accb + (20 + q) * 64 + p4 * 4);
        const float denom = ((float)S_ - accb[2644 + q]) + accb[2624 + q];
        const float inv = 1.0f / denom;
        const float4 pv = ((const float4*)px)[idx];
        const float om = 1.0f - c;
        float4 o;
        o.x = c * pv.x + om * ((T.x - G.x + E.x) * inv);
        o.y = c * pv.y + om * ((T.y - G.y + E.y) * inv);
        o.z = c * pv.z + om * ((T.z - G.z + E.z) * inv);
        o.w = c * pv.w + om * ((T.w - G.w + E.w) * inv);
        ((float4*)out)[idx] = o;
    }
}

// ---------------------------------------------------------------------------
extern "C" void kernel_launch(void* const* d_in, const int* in_sizes, int n_in,
                              void* d_out, int out_size, void* d_ws, size_t ws_size,
                              hipStream_t stream) {
    const float* fx  = (const float*)d_in[0];
    const float* px  = (const float*)d_in[1];
    const float* sw1 = (const float*)d_in[2];
    const float* sb1 = (const float*)d_in[3];
    const float* sw2 = (const float*)d_in[4];
    const float* sb2 = (const float*)d_in[5];
    const float* cw1 = (const float*)d_in[6];
    const float* cb1 = (const float*)d_in[7];
    const float* cw2 = (const float*)d_in[8];
    const float* cb2 = (const float*)d_in[9];
    const int* questions = (const int*)d_in[10];
    float* out = (float*)d_out;
    float* ws  = (float*)d_ws;

    void* args[] = {(void*)&fx, (void*)&px, (void*)&sw1, (void*)&sb1, (void*)&sw2,
                    (void*)&sb2, (void*)&cw1, (void*)&cb1, (void*)&cw2, (void*)&cb2,
                    (void*)&questions, (void*)&out, (void*)&ws};
    hipLaunchCooperativeKernel((void*)mega_kernel, dim3(512), dim3(256), args, 0, stream);
}

// Round 5
// 113.786 us; speedup vs baseline: 4.3645x; 4.3645x over previous
//
#include <hip/hip_runtime.h>
#include <math.h>

#define B_  8
#define S_  2048
#define H_  256
#define HK_ 128
#define P_  64
#define NQ_ 20
#define M_  (B_*S_)          // 16384 rows
// per-batch accumulator: G[20][64]@0, E[20][64]@1280, T[64]@2560, W[20]@2624, n[20]@2644, pad->2688
#define ACC_STRIDE 2688

// ws layout (float units)
#define WS_CONF  0                // 16384 floats
#define WS_ACC   16384            // 8*2688 = 21504 floats
#define WS_WT    37888            // bf16 frags: 2*8*8*64*8 = 65536 shorts = 32768 float slots

typedef __attribute__((ext_vector_type(8))) short bf16x8;
typedef __attribute__((ext_vector_type(4))) float f32x4;

// ---------------------------------------------------------------------------
// Kernel 0: prep — round w1 (fp32 [k=256][n=128]) RNE to bf16 into MFMA
// B-fragment order wtf[mlp][kt(8)][nt(8)][lane(64)][j(8)], and zero ws_acc.
// 8192 threads, each writes one 16B fragment.
// ---------------------------------------------------------------------------
__global__ void prep_kernel(const float* __restrict__ sw1, const float* __restrict__ cw1,
                            short* __restrict__ wtf, float* __restrict__ ws_acc)
{
    const int t = blockIdx.x * 256 + threadIdx.x;      // 0..8191
    const int l = t & 63, nt = (t >> 6) & 7, kt = (t >> 9) & 7, mlp = t >> 12;
    const int col = l & 15, quad = l >> 4;
    const int n = nt * 16 + col;
    const float* w1 = mlp ? cw1 : sw1;
    short frag[8];
    #pragma unroll
    for (int j = 0; j < 8; ++j) {
        int k = kt * 32 + quad * 8 + j;
        union { float f; unsigned u; } c; c.f = w1[k * HK_ + n];
        frag[j] = (short)((c.u + 0x7FFF + ((c.u >> 16) & 1)) >> 16);   // RNE
    }
    *(uint4*)(wtf + (size_t)t * 8) = *(const uint4*)frag;
    for (int s = t; s < B_ * ACC_STRIDE; s += 8192) ws_acc[s] = 0.f;
}

// ---------------------------------------------------------------------------
// Kernel 1: dual MLP via bf16 MFMA (16x16x32), 2-term A-split (Ahi+Alo),
// B-fragments straight from global (L2-broadcast, fragment-ordered), fused
// fp32 layer-2 epilogue, THEN fused bucketed accumulation for the block's
// own 32 rows (e^sim stashed in LDS; per-block LDS reduction; one device
// atomicAdd flush of 2688 floats). sim never touches global memory.
// Block = 4 waves; wave w: mlp=w>>1, row-tile mt=w&1 (32 rows/block).
// ---------------------------------------------------------------------------
__launch_bounds__(256)
__global__ void mlp_accum_kernel(const float* __restrict__ fx, const short* __restrict__ wtf,
                                 const float* __restrict__ px, const int* __restrict__ questions,
                                 const float* __restrict__ sb1, const float* __restrict__ sw2,
                                 const float* __restrict__ sb2, const float* __restrict__ cb1,
                                 const float* __restrict__ cw2, const float* __restrict__ cb2,
                                 float* __restrict__ conf_g, float* __restrict__ ws_acc)
{
    const int tid = threadIdx.x;
    const int bid = blockIdx.x;
    const int w   = tid >> 6, l = tid & 63;
    const int col = l & 15, quad = l >> 4;
    const int mlp = w >> 1, mt = w & 1;
    const int row = bid * 32 + mt * 16 + col;          // A-operand m = lane&15

    __shared__ float accs[ACC_STRIDE];                 // 10.5 KB
    __shared__ float ev[32];                           // e^sim per local row
    __shared__ int   qflag[NQ_];
    for (int s = tid; s < ACC_STRIDE; s += 256) accs[s] = 0.f;
    if (tid < NQ_) qflag[tid] = 0;

    f32x4 acc[8];
    #pragma unroll
    for (int nt = 0; nt < 8; ++nt) acc[nt] = (f32x4){0.f, 0.f, 0.f, 0.f};

    const float* fxrow = fx + (size_t)row * H_;
    const short* wf = wtf + (size_t)mlp * 32768 + (size_t)l * 8;

    #pragma unroll
    for (int kt = 0; kt < 8; ++kt) {
        float4 a0 = *(const float4*)(fxrow + kt * 32 + quad * 8);
        float4 a1 = *(const float4*)(fxrow + kt * 32 + quad * 8 + 4);
        float af[8] = {a0.x, a0.y, a0.z, a0.w, a1.x, a1.y, a1.z, a1.w};
        bf16x8 ahi, alo;
        #pragma unroll
        for (int i = 0; i < 8; ++i) {
            union { float f; unsigned u; } c; c.f = af[i];
            unsigned hi = c.u >> 16;                   // truncate: lo holds residual
            ahi[i] = (short)hi;
            union { float f; unsigned u; } h2; h2.u = hi << 16;
            union { float f; unsigned u; } c2; c2.f = af[i] - h2.f;
            alo[i] = (short)(c2.u >> 16);
        }
        const short* base = wf + (size_t)kt * 4096;
        #pragma unroll
        for (int nt = 0; nt < 8; ++nt) {
            bf16x8 bf = *(const bf16x8*)(base + nt * 512);
            acc[nt] = __builtin_amdgcn_mfma_f32_16x16x32_bf16(ahi, bf, acc[nt], 0, 0, 0);
            acc[nt] = __builtin_amdgcn_mfma_f32_16x16x32_bf16(alo, bf, acc[nt], 0, 0, 0);
        }
    }

    // fp32 layer-2 epilogue
    const float* b1 = mlp ? cb1 : sb1;
    const float* w2 = mlp ? cw2 : sw2;
    const float  b2v = mlp ? cb2[0] : sb2[0];
    float p[4] = {0.f, 0.f, 0.f, 0.f};
    #pragma unroll
    for (int nt = 0; nt < 8; ++nt) {
        float b1c = b1[nt * 16 + col];
        float w2c = w2[nt * 16 + col];
        #pragma unroll
        for (int j = 0; j < 4; ++j)
            p[j] += fmaxf(acc[nt][j] + b1c, 0.f) * w2c;
    }
    #pragma unroll
    for (int off = 8; off >= 1; off >>= 1)
        #pragma unroll
        for (int j = 0; j < 4; ++j) p[j] += __shfl_down(p[j], off, 16);

    if (col == 0) {
        #pragma unroll
        for (int j = 0; j < 4; ++j) {
            int rl = mt * 16 + quad * 4 + j;           // local row 0..31 (D row = quad*4+reg)
            float v = p[j] + b2v;
            if (mlp == 0) ev[rl] = expf(v);            // e^sim, consumed below
            else          conf_g[bid * 32 + rl] = 1.0f / (1.0f + expf(-v));
        }
    }
    __syncthreads();

    // ---- fused accum: this block's 32 rows (all in batch b = bid>>6) ----
    const int b = bid >> 6;
    const int i_s0 = (bid & 63) * 32;
    const int* qb = questions + b * S_;
    const float* pxb = px + (size_t)b * S_ * P_;

    float Treg = 0.f;
    #pragma unroll
    for (int t = 0; t < 8; ++t) {
        int rl = w * 8 + t;                            // wave handles 8 rows
        int i_s = i_s0 + rl;
        int qi = qb[i_s];                              // wave-uniform -> s_load
        float e = ev[rl];                              // LDS broadcast
        float v = pxb[(size_t)i_s * P_ + l];           // coalesced 256B per wave
        Treg += v;
        atomicAdd(&accs[qi * 64 + l], v);              // G_q
        atomicAdd(&accs[1280 + qi * 64 + l], e * v);   // E_q
        if (l == 0) {
            atomicAdd(&accs[2624 + qi], e);            // W_q
            atomicAdd(&accs[2644 + qi], 1.0f);         // n_q
            qflag[qi] = 1;                             // benign race, same value
        }
    }
    atomicAdd(&accs[2560 + l], Treg);                  // T
    __syncthreads();

    // flush (skip G/E rows for absent q)
    float* dst = ws_acc + (size_t)b * ACC_STRIDE;
    for (int s = tid; s < ACC_STRIDE; s += 256) {
        int q = (s < 1280) ? (s >> 6) : (s < 2560) ? ((s - 1280) >> 6) : -1;
        if (q >= 0 && !qflag[q]) continue;
        atomicAdd(dst + s, accs[s]);
    }
}

// ---------------------------------------------------------------------------
// Kernel 2: out = c*px + (1-c) * ((T - G_q + E_q) / ((S-n_q)+W_q)), float4/thread
// ---------------------------------------------------------------------------
__global__ void output_kernel(const float* __restrict__ px, const float* __restrict__ conf,
                              const int* __restrict__ questions, const float* __restrict__ ws_acc,
                              float* __restrict__ out)
{
    const int idx = blockIdx.x * 256 + threadIdx.x;  // float4 units, 262144 total
    const int row = idx >> 4;                        // b*S + s
    const int p4  = idx & 15;
    const int b   = row >> 11;                       // S = 2048
    const float c = conf[row];
    const int   q = questions[row];
    const float* accb = ws_acc + (size_t)b * ACC_STRIDE;
    const float4 T = *(const float4*)(accb + 2560 + p4 * 4);
    const float4 G = *(const float4*)(accb + q * 64 + p4 * 4);
    const float4 E = *(const float4*)(accb + (20 + q) * 64 + p4 * 4);
    const float denom = ((float)S_ - accb[2644 + q]) + accb[2624 + q];
    const float inv = 1.0f / denom;
    const float4 pv = ((const float4*)px)[idx];
    const float om = 1.0f - c;
    float4 o;
    o.x = c * pv.x + om * ((T.x - G.x + E.x) * inv);
    o.y = c * pv.y + om * ((T.y - G.y + E.y) * inv);
    o.z = c * pv.z + om * ((T.z - G.z + E.z) * inv);
    o.w = c * pv.w + om * ((T.w - G.w + E.w) * inv);
    ((float4*)out)[idx] = o;
}

// ---------------------------------------------------------------------------
extern "C" void kernel_launch(void* const* d_in, const int* in_sizes, int n_in,
                              void* d_out, int out_size, void* d_ws, size_t ws_size,
                              hipStream_t stream) {
    const float* fx  = (const float*)d_in[0];
    const float* px  = (const float*)d_in[1];
    const float* sw1 = (const float*)d_in[2];
    const float* sb1 = (const float*)d_in[3];
    const float* sw2 = (const float*)d_in[4];
    const float* sb2 = (const float*)d_in[5];
    const float* cw1 = (const float*)d_in[6];
    const float* cb1 = (const float*)d_in[7];
    const float* cw2 = (const float*)d_in[8];
    const float* cb2 = (const float*)d_in[9];
    const int* questions = (const int*)d_in[10];
    float* out = (float*)d_out;

    float* ws     = (float*)d_ws;
    float* conf   = ws + WS_CONF;
    float* ws_acc = ws + WS_ACC;
    short* wtf    = (short*)(ws + WS_WT);

    prep_kernel<<<32, 256, 0, stream>>>(sw1, cw1, wtf, ws_acc);
    mlp_accum_kernel<<<M_ / 32, 256, 0, stream>>>(fx, wtf, px, questions,
                                                  sb1, sw2, sb2, cb1, cw2, cb2,
                                                  conf, ws_acc);
    output_kernel<<<(M_ * P_ / 4) / 256, 256, 0, stream>>>(px, conf, questions,
                                                           ws_acc, out);
}